// Round 6
// baseline (215.423 us; speedup 1.0000x reference)
//
#include <hip/hip_runtime.h>

// out[b, w, j] = sum_p x[b,j,p] * weight[j,p,w] + bias[j,w]
// x: [B,M,P] f32, weight: [M,P,W] f32, bias: [M,W] f32, out: [B,W,M] f32
// B=128, M=10000, P=64, W=24. HBM floor ~520-560 MB -> ~85 us.
//
// Round-6: JT=16 restores full-64B-sector store runs (round-5's JT=8 32B runs
// caused TCC write-allocate: WRITE 120->169 MB, FETCH +87 MB). Thread = 4 b x
// 6 w (acc 24 regs) keeps live set < 64 VGPR so the compiler doesn't remat
// LDS weight reads (round-5: VGPR=64 forced remat, VALUBusy 22->12%).
// Weight LDS reads: 3x ds_read_b64 per p, 4 distinct addrs/instr, conflict-
// free. Pair-swizzle puts (jt,by=0),(jt,by=1) on same XCD -> weight L2 share.

constexpr int B  = 128;
constexpr int M  = 10000;
constexpr int P  = 64;
constexpr int W  = 24;

constexpr int JT  = 16;          // j per block (= waves, wave = one j)
constexpr int BH  = 64;          // b per block
constexpr int NT  = 1024;        // 16 waves
constexpr int NWG = (M / JT) * (B / BH);  // 1250
constexpr int OPD = 18;          // obuf bl-pad: drain 2-way (free)

__global__ __launch_bounds__(NT, 4) void pcl_kernel(
    const float* __restrict__ x, const float* __restrict__ wgt,
    const float* __restrict__ bias, float* __restrict__ out) {
  __shared__ float wlds[JT * P * W];   // 96 KiB, [j][p][w] == global layout
  __shared__ float obuf[W][JT][OPD];   // 27,648 B (total 125,952)

  const int t = threadIdx.x;

  // bijective XCD swizzle (m204): 1250 = 8*156 + 2
  const int orig = blockIdx.x;
  const int xcd  = orig & 7;
  const int idx  = orig >> 3;
  const int wgid = (xcd < 2 ? xcd * 157 : 314 + (xcd - 2) * 156) + idx;
  const int jt = wgid >> 1;  // (jt,0),(jt,1) consecutive on same XCD
  const int by = wgid & 1;
  const int j0 = jt * JT;
  const int b0 = by * BH;

  // ---- stage weight tile: straight coalesced float4 copy ----
  {
    const float4* wg4 =
        reinterpret_cast<const float4*>(wgt + (size_t)j0 * (P * W));
    float4* wl4 = reinterpret_cast<float4*>(wlds);
#pragma unroll
    for (int k = 0; k < (JT * P * W / 4) / NT; ++k)  // 6 float4/thread
      wl4[t + k * NT] = wg4[t + k * NT];
  }

  const int jw   = t >> 6;      // wave = local j
  const int lane = t & 63;
  const int bl   = lane & 15;   // b-lane
  const int wh   = lane >> 4;   // w quarter (0..3)
  const int w0   = 6 * wh;
  const int j    = j0 + jw;

  // bias -> acc[4][6]
  float acc[4][6];
  {
    const float2* bp =
        reinterpret_cast<const float2*>(bias + (size_t)j * W + w0);
    float2 bA = bp[0], bB = bp[1], bC = bp[2];
#pragma unroll
    for (int bi = 0; bi < 4; ++bi) {
      acc[bi][0] = bA.x; acc[bi][1] = bA.y;
      acc[bi][2] = bB.x; acc[bi][3] = bB.y;
      acc[bi][4] = bC.x; acc[bi][5] = bC.y;
    }
  }

  // 4 independent x streams (b = b0 + bl + 16*bi); 4 wh-lanes share addresses
  const float4* xp0 = reinterpret_cast<const float4*>(x + ((size_t)(b0 + bl +  0) * M + j) * P);
  const float4* xp1 = reinterpret_cast<const float4*>(x + ((size_t)(b0 + bl + 16) * M + j) * P);
  const float4* xp2 = reinterpret_cast<const float4*>(x + ((size_t)(b0 + bl + 32) * M + j) * P);
  const float4* xp3 = reinterpret_cast<const float4*>(x + ((size_t)(b0 + bl + 48) * M + j) * P);

  const float* wb = wlds + jw * (P * W) + w0;

  __syncthreads();  // weights staged

  // ---- compute: per chunk (4 p's): 4 global float4, 12 ds_read_b64, 96 FMA
#pragma unroll 2
  for (int c = 0; c < P / 4; ++c) {
    float4 xv0 = xp0[c], xv1 = xp1[c], xv2 = xp2[c], xv3 = xp3[c];
#pragma unroll
    for (int pp = 0; pp < 4; ++pp) {
      const float2* wp =
          reinterpret_cast<const float2*>(wb + (4 * c + pp) * W);
      const float2 wA = wp[0], wB = wp[1], wC = wp[2];
      const float xs0 = pp == 0 ? xv0.x : pp == 1 ? xv0.y : pp == 2 ? xv0.z : xv0.w;
      const float xs1 = pp == 0 ? xv1.x : pp == 1 ? xv1.y : pp == 2 ? xv1.z : xv1.w;
      const float xs2 = pp == 0 ? xv2.x : pp == 1 ? xv2.y : pp == 2 ? xv2.z : xv2.w;
      const float xs3 = pp == 0 ? xv3.x : pp == 1 ? xv3.y : pp == 2 ? xv3.z : xv3.w;
#define FMA6(A, XS)                                                       \
      A[0] = fmaf(XS, wA.x, A[0]); A[1] = fmaf(XS, wA.y, A[1]);           \
      A[2] = fmaf(XS, wB.x, A[2]); A[3] = fmaf(XS, wB.y, A[3]);           \
      A[4] = fmaf(XS, wC.x, A[4]); A[5] = fmaf(XS, wC.y, A[5]);
      FMA6(acc[0], xs0)
      FMA6(acc[1], xs1)
      FMA6(acc[2], xs2)
      FMA6(acc[3], xs3)
#undef FMA6
    }
  }

  // ---- store: 4 rounds (one per bi); transpose via obuf; 64B j-runs ----
#pragma unroll
  for (int r = 0; r < 4; ++r) {
    __syncthreads();  // previous round's drain reads done
#pragma unroll
    for (int ww = 0; ww < 6; ++ww) obuf[w0 + ww][jw][bl] = acc[r][ww];
    __syncthreads();  // obuf visible
#pragma unroll
    for (int it = 0; it < 2; ++it) {
      const int d = t + it * NT;
      if (d < W * JT * 16 / 4) {  // 1536 float4 per round
        const int jq  = d & 3;
        const int blr = (d >> 2) & 15;
        const int w   = d >> 6;  // 0..23
        float4 o;
        o.x = obuf[w][4 * jq + 0][blr];
        o.y = obuf[w][4 * jq + 1][blr];
        o.z = obuf[w][4 * jq + 2][blr];
        o.w = obuf[w][4 * jq + 3][blr];
        *reinterpret_cast<float4*>(
            out + ((size_t)(b0 + 16 * r + blr) * W + w) * M + j0 + 4 * jq) = o;
      }
    }
  }
}

extern "C" void kernel_launch(void* const* d_in, const int* in_sizes, int n_in,
                              void* d_out, int out_size, void* d_ws, size_t ws_size,
                              hipStream_t stream) {
  const float* x    = (const float*)d_in[0];
  const float* wgt  = (const float*)d_in[1];
  const float* bias = (const float*)d_in[2];
  float* out        = (float*)d_out;

  dim3 grid(NWG);  // 1250
  dim3 block(NT);  // 1024
  hipLaunchKernelGGL(pcl_kernel, grid, block, 0, stream, x, wgt, bias, out);
}